// Round 3
// baseline (631.257 us; speedup 1.0000x reference)
//
#include <hip/hip_runtime.h>
#include <hip/hip_bf16.h>
#include <math.h>
#include <stdint.h>

#define B_    32
#define S_    512
#define H_    768
#define NH_   12
#define HD_   64
#define NCOL_ 32
#define M_    (B_*S_)   // 16384

typedef __bf16 bf16;
typedef __bf16 bf16x8 __attribute__((ext_vector_type(8)));
typedef float  f32x4  __attribute__((ext_vector_type(4)));

// ---------------------------------------------------------------------------
// dtype-flexible loads: flag selects fp32 (convert to bf16) vs native bf16
// ---------------------------------------------------------------------------
__device__ __forceinline__ bf16x8 load8(const void* base, long elem, bool f32) {
    bf16x8 r;
    if (f32) {
        const float4* fp = (const float4*)((const float*)base + elem);
        float4 x = fp[0], y = fp[1];
        r[0] = (bf16)x.x; r[1] = (bf16)x.y; r[2] = (bf16)x.z; r[3] = (bf16)x.w;
        r[4] = (bf16)y.x; r[5] = (bf16)y.y; r[6] = (bf16)y.z; r[7] = (bf16)y.w;
    } else {
        r = *(const bf16x8*)((const bf16*)base + elem);
    }
    return r;
}

__device__ __forceinline__ float loadf(const void* base, long elem, bool f32) {
    return f32 ? ((const float*)base)[elem] : (float)((const bf16*)base)[elem];
}

// ---------------------------------------------------------------------------
// dtype detect: Wd ~ N(0, 0.02^2). As u16 stream: bf16 buffer -> exponent
// field always < 127; fp32 buffer -> even u16s are mantissa halves (uniform),
// ~50% have exp >= 127. Count over 2048 u16s, threshold 64.
// ---------------------------------------------------------------------------
__global__ void detect_kernel(const unsigned short* __restrict__ wd, int* __restrict__ flag)
{
    int lane = threadIdx.x;   // 64 threads
    int big = 0;
    for (int i = 0; i < 32; i++) {
        unsigned short p = wd[lane * 32 + i];
        int e = (p >> 7) & 0xFF;
        if (e >= 127) big++;
    }
    for (int m = 1; m < 64; m <<= 1) big += __shfl_xor(big, m);
    if (lane == 0) *flag = (big > 64) ? 1 : 0;
}

// ---------------------------------------------------------------------------
// gather: h_col[row,:] = (vm==0 || cat!=1) ? 0 : column_embeddings[b, vm-1, :]
// ---------------------------------------------------------------------------
__global__ void gather_kernel(const void* __restrict__ ce, const int* __restrict__ cc,
                              const int* __restrict__ vm, bf16* __restrict__ hcol,
                              const int* __restrict__ flag)
{
    const bool f32 = (*flag) != 0;
    int id  = blockIdx.x * 256 + threadIdx.x;       // [0, M_*96)
    int row = id / 96;
    int c   = id - row * 96;                        // 8-elem chunk within row
    int b   = row >> 9;
    int m   = vm[row];
    bf16x8 val;
#pragma unroll
    for (int i = 0; i < 8; i++) val[i] = (bf16)0.0f;
    if (m > 0) {
        int col = m - 1;
        if (cc[b * NCOL_ + col] == 1)
            val = load8(ce, ((long)(b * NCOL_ + col)) * H_ + c * 8, f32);
    }
    *(bf16x8*)&hcol[(long)row * H_ + c * 8] = val;
}

// ---------------------------------------------------------------------------
// GEMM C[m,n] = sum_k A[m,k]*Bw[n,k]  (+ epilogue per MODE)
// A split at KSPLIT between A0/A1 (row stride 768 each), same for Bw.
// A0E/A1E: that A segment is an external input (dtype per flag) vs internal bf16.
// B and biases are always external. resid/out always internal bf16.
// 128x128 tile, BK=32, 256 threads, 16x16x32 bf16 MFMA.
// MODE 0: gelu(acc+bias1+bias2) -> [M,768] bf16
// MODE 1: acc+bias1 -> [B,NH,S,HD] bf16
// MODE 2: acc+bias1+resid -> [M,768] bf16
// ---------------------------------------------------------------------------
template<int MODE, bool A0E, bool A1E>
__global__ __launch_bounds__(256) void gemm_bt(
    const void* __restrict__ A0, const void* __restrict__ A1,
    const void* __restrict__ B0, const void* __restrict__ B1,
    const void* __restrict__ bias1, const void* __restrict__ bias2,
    const bf16* __restrict__ resid, bf16* __restrict__ out,
    int K, int KSPLIT, const int* __restrict__ flag)
{
    __shared__ __align__(16) bf16 As[128 * 32];
    __shared__ __align__(16) bf16 Bs[128 * 32];

    const bool f32 = (*flag) != 0;
    const int tid  = threadIdx.x;
    const int lane = tid & 63;
    const int wave = tid >> 6;
    const int wm   = wave & 1;
    const int wn   = wave >> 1;
    const int m0   = blockIdx.x * 128;
    const int n0   = blockIdx.y * 128;

    const int srow = tid >> 2;            // 0..63
    const int scol = (tid & 3) * 8;       // 0,8,16,24

    f32x4 acc[4][4];
    const f32x4 zero4 = {0.f, 0.f, 0.f, 0.f};
#pragma unroll
    for (int i = 0; i < 4; i++)
#pragma unroll
        for (int j = 0; j < 4; j++) acc[i][j] = zero4;

    const int a_off = (wm * 64 + (lane & 15)) * 32 + (lane >> 4) * 8;
    const int b_off = (wn * 64 + (lane & 15)) * 32 + (lane >> 4) * 8;

    for (int k0 = 0; k0 < K; k0 += 32) {
        const void* ab; const void* bb; int ke; bool aE;
        if (k0 < KSPLIT) { ab = A0; bb = B0; ke = k0;          aE = A0E; }
        else             { ab = A1; bb = B1; ke = k0 - KSPLIT; aE = A1E; }
        const bool af = aE && f32;

        bf16x8 a0v = load8(ab, (long)(m0 + srow) * H_ + ke + scol, af);
        bf16x8 a1v = load8(ab, (long)(m0 + 64 + srow) * H_ + ke + scol, af);
        bf16x8 b0v = load8(bb, (long)(n0 + srow) * H_ + ke + scol, f32);
        bf16x8 b1v = load8(bb, (long)(n0 + 64 + srow) * H_ + ke + scol, f32);

        __syncthreads();   // previous iteration's LDS reads complete
        *(bf16x8*)&As[srow * 32 + scol]        = a0v;
        *(bf16x8*)&As[(64 + srow) * 32 + scol] = a1v;
        *(bf16x8*)&Bs[srow * 32 + scol]        = b0v;
        *(bf16x8*)&Bs[(64 + srow) * 32 + scol] = b1v;
        __syncthreads();   // stores visible to all waves

        bf16x8 afr[4], bfr[4];
#pragma unroll
        for (int i = 0; i < 4; i++) afr[i] = *(const bf16x8*)(As + a_off + i * 512);
#pragma unroll
        for (int j = 0; j < 4; j++) bfr[j] = *(const bf16x8*)(Bs + b_off + j * 512);
#pragma unroll
        for (int i = 0; i < 4; i++)
#pragma unroll
            for (int j = 0; j < 4; j++)
                acc[i][j] = __builtin_amdgcn_mfma_f32_16x16x32_bf16(afr[i], bfr[j], acc[i][j], 0, 0, 0);
    }

    const int c_r = (lane >> 4) * 4;
    const int c_c = lane & 15;
#pragma unroll
    for (int j = 0; j < 4; j++) {
        const int col = n0 + wn * 64 + j * 16 + c_c;
        float bias = loadf(bias1, col, f32);
        if (MODE == 0) bias += loadf(bias2, col, f32);
#pragma unroll
        for (int i = 0; i < 4; i++) {
#pragma unroll
            for (int r = 0; r < 4; r++) {
                const int row = m0 + wm * 64 + i * 16 + c_r + r;
                float v = acc[i][j][r] + bias;
                if (MODE == 0) {
                    v = 0.5f * v * (1.0f + erff(v * 0.70710678118654752f));
                    out[(long)row * H_ + col] = (bf16)v;
                } else if (MODE == 1) {
                    int b = row >> 9, s = row & 511;
                    int head = col >> 6, d = col & 63;
                    out[(((long)(b * NH_ + head)) * S_ + s) * HD_ + d] = (bf16)v;
                } else {
                    v += (float)resid[(long)row * H_ + col];
                    out[(long)row * H_ + col] = (bf16)v;
                }
            }
        }
    }
}

// ---------------------------------------------------------------------------
// flash attention: one block per (qt, head, b); 64 q rows, k-chunks of 64.
// q,k,v internal [B,NH,S,HD] bf16. ctx out internal [B,S,H] bf16.
// ---------------------------------------------------------------------------
#define PS 88   // padded LDS row stride (elems): 176B, 16B-aligned

__global__ __launch_bounds__(256) void attn_kernel(
    const bf16* __restrict__ q, const bf16* __restrict__ k,
    const bf16* __restrict__ v, bf16* __restrict__ ctx)
{
    __shared__ __align__(16) bf16 Qs[64 * PS];
    __shared__ __align__(16) bf16 Ks[64 * PS];
    __shared__ __align__(16) bf16 Vt[64 * PS];      // transposed: Vt[d][s]
    __shared__ __align__(16) bf16 Ps[4][16 * PS];   // per-wave P tile

    const int tid  = threadIdx.x;
    const int lane = tid & 63;
    const int w    = tid >> 6;
    const int qt = blockIdx.x, h = blockIdx.y, b = blockIdx.z;
    const long base = ((long)(b * NH_ + h)) * S_ * HD_;

    {
        const bf16* qg = q + base + (long)qt * 64 * HD_;
        int c0 = tid * 2;
#pragma unroll
        for (int c = c0; c < c0 + 2; c++) {
            int row = c >> 3, cc = c & 7;
            *(uint4*)&Qs[row * PS + cc * 8] = *(const uint4*)&qg[row * HD_ + cc * 8];
        }
    }
    __syncthreads();

    const int fr = (lane >> 4) * 8;
    const bf16x8 aq0 = *(const bf16x8*)&Qs[(w * 16 + (lane & 15)) * PS + fr];
    const bf16x8 aq1 = *(const bf16x8*)&Qs[(w * 16 + (lane & 15)) * PS + 32 + fr];

    f32x4 O[4];
    const f32x4 zero4 = {0.f, 0.f, 0.f, 0.f};
#pragma unroll
    for (int t = 0; t < 4; t++) O[t] = zero4;
    float mo[4], l[4];
#pragma unroll
    for (int r = 0; r < 4; r++) { mo[r] = -1e30f; l[r] = 0.f; }

    const int vs = tid >> 2;          // s row for V transpose
    const int vd = (tid & 3) * 16;    // d base

    for (int kc = 0; kc < 8; kc++) {
        __syncthreads();
        const bf16* kg = k + base + (long)kc * 64 * HD_;
        const bf16* vg = v + base + (long)kc * 64 * HD_;
        {
            int c0 = tid * 2;
#pragma unroll
            for (int c = c0; c < c0 + 2; c++) {
                int row = c >> 3, cc = c & 7;
                *(uint4*)&Ks[row * PS + cc * 8] = *(const uint4*)&kg[row * HD_ + cc * 8];
            }
            uint4 p0 = *(const uint4*)&vg[vs * HD_ + vd];
            uint4 p1 = *(const uint4*)&vg[vs * HD_ + vd + 8];
            const bf16* e0 = (const bf16*)&p0;
            const bf16* e1 = (const bf16*)&p1;
#pragma unroll
            for (int i = 0; i < 8; i++) Vt[(vd + i) * PS + vs]     = e0[i];
#pragma unroll
            for (int i = 0; i < 8; i++) Vt[(vd + 8 + i) * PS + vs] = e1[i];
        }
        __syncthreads();

        f32x4 sc[4];
#pragma unroll
        for (int j = 0; j < 4; j++) {
            sc[j] = zero4;
            bf16x8 b0 = *(const bf16x8*)&Ks[(j * 16 + (lane & 15)) * PS + fr];
            bf16x8 b1 = *(const bf16x8*)&Ks[(j * 16 + (lane & 15)) * PS + 32 + fr];
            sc[j] = __builtin_amdgcn_mfma_f32_16x16x32_bf16(aq0, b0, sc[j], 0, 0, 0);
            sc[j] = __builtin_amdgcn_mfma_f32_16x16x32_bf16(aq1, b1, sc[j], 0, 0, 0);
        }

#pragma unroll
        for (int r = 0; r < 4; r++) {
            float s0 = sc[0][r] * 0.125f, s1 = sc[1][r] * 0.125f;
            float s2 = sc[2][r] * 0.125f, s3 = sc[3][r] * 0.125f;
            float rm = fmaxf(fmaxf(s0, s1), fmaxf(s2, s3));
            rm = fmaxf(rm, __shfl_xor(rm, 1));
            rm = fmaxf(rm, __shfl_xor(rm, 2));
            rm = fmaxf(rm, __shfl_xor(rm, 4));
            rm = fmaxf(rm, __shfl_xor(rm, 8));
            float mn = fmaxf(mo[r], rm);
            float alpha = __expf(mo[r] - mn);
            s0 = __expf(s0 - mn); s1 = __expf(s1 - mn);
            s2 = __expf(s2 - mn); s3 = __expf(s3 - mn);
            float rs = s0 + s1 + s2 + s3;
            rs += __shfl_xor(rs, 1);
            rs += __shfl_xor(rs, 2);
            rs += __shfl_xor(rs, 4);
            rs += __shfl_xor(rs, 8);
            l[r] = l[r] * alpha + rs;
            mo[r] = mn;
#pragma unroll
            for (int t = 0; t < 4; t++) O[t][r] *= alpha;
            int prow = (lane >> 4) * 4 + r;
            Ps[w][prow * PS +      (lane & 15)] = (bf16)s0;
            Ps[w][prow * PS + 16 + (lane & 15)] = (bf16)s1;
            Ps[w][prow * PS + 32 + (lane & 15)] = (bf16)s2;
            Ps[w][prow * PS + 48 + (lane & 15)] = (bf16)s3;
        }
        __syncthreads();

#pragma unroll
        for (int hh = 0; hh < 2; hh++) {
            bf16x8 ap = *(const bf16x8*)&Ps[w][(lane & 15) * PS + hh * 32 + fr];
#pragma unroll
            for (int t = 0; t < 4; t++) {
                bf16x8 bv = *(const bf16x8*)&Vt[(t * 16 + (lane & 15)) * PS + hh * 32 + fr];
                O[t] = __builtin_amdgcn_mfma_f32_16x16x32_bf16(ap, bv, O[t], 0, 0, 0);
            }
        }
    }

#pragma unroll
    for (int r = 0; r < 4; r++) {
        float inv = 1.0f / l[r];
        int s = qt * 64 + w * 16 + (lane >> 4) * 4 + r;
#pragma unroll
        for (int t = 0; t < 4; t++) {
            int d = t * 16 + (lane & 15);
            ctx[((long)(b * S_ + s)) * H_ + h * HD_ + d] = (bf16)(O[t][r] * inv);
        }
    }
}

// ---------------------------------------------------------------------------
// layernorm: one wave per row; input internal bf16, output per-flag dtype
// ---------------------------------------------------------------------------
__global__ __launch_bounds__(256) void ln_kernel(
    const bf16* __restrict__ y, const void* __restrict__ g,
    const void* __restrict__ be, void* __restrict__ out,
    const int* __restrict__ flag)
{
    const bool f32 = (*flag) != 0;
    const int lane = threadIdx.x & 63;
    const int w    = threadIdx.x >> 6;
    const long row = (long)blockIdx.x * 4 + w;
    const bf16* yr = y + row * H_;

    float x[12];
    float sum = 0.f, ss = 0.f;
#pragma unroll
    for (int j = 0; j < 12; j++) {
        x[j] = (float)yr[j * 64 + lane];
        sum += x[j];
        ss  += x[j] * x[j];
    }
#pragma unroll
    for (int m = 1; m < 64; m <<= 1) {
        sum += __shfl_xor(sum, m);
        ss  += __shfl_xor(ss, m);
    }
    const float mu  = sum * (1.0f / 768.0f);
    float var = ss * (1.0f / 768.0f) - mu * mu;
    const float rs = rsqrtf(fmaxf(var, 0.f) + 1e-12f);
#pragma unroll
    for (int j = 0; j < 12; j++) {
        int c = j * 64 + lane;
        float r = (x[j] - mu) * rs * loadf(g, c, f32) + loadf(be, c, f32);
        if (f32) ((float*)out)[row * H_ + c] = r;
        else     ((bf16*)out)[row * H_ + c]  = (bf16)r;
    }
}

// ---------------------------------------------------------------------------
extern "C" void kernel_launch(void* const* d_in, const int* in_sizes, int n_in,
                              void* d_out, int out_size, void* d_ws, size_t ws_size,
                              hipStream_t stream)
{
    const void* hidden = d_in[0];
    const void* ce     = d_in[1];
    const int*  cc     = (const int*)d_in[2];
    const int*  vm     = (const int*)d_in[3];
    const void* Wd     = d_in[4];
    const void* bd     = d_in[5];
    const void* Wc     = d_in[6];
    const void* bc     = d_in[7];
    const void* Wq     = d_in[8];
    const void* bq     = d_in[9];
    const void* Wk     = d_in[10];
    const void* bk     = d_in[11];
    const void* Wv     = d_in[12];
    const void* bv     = d_in[13];
    const void* Wo     = d_in[14];
    const void* bo     = d_in[15];
    const void* lng    = d_in[16];
    const void* lnb    = d_in[17];

    // workspace: 5 bf16 buffers x 24 MB + flag word
    char* ws = (char*)d_ws;
    const size_t sz = (size_t)M_ * H_ * sizeof(bf16);   // 25165824 B
    bf16* hcol = (bf16*)(ws);            // later reused as ctx
    bf16* hbuf = (bf16*)(ws + sz);
    bf16* qb   = (bf16*)(ws + 2 * sz);   // later reused as y (pre-LN)
    bf16* kb   = (bf16*)(ws + 3 * sz);
    bf16* vb   = (bf16*)(ws + 4 * sz);
    int*  flag = (int*)(ws + 5 * sz);
    bf16* ctx  = hcol;                   // hcol dead after GEMM1
    bf16* y    = qb;                     // qb dead after attention

    detect_kernel<<<1, 64, 0, stream>>>((const unsigned short*)Wd, flag);
    gather_kernel<<<M_ * 96 / 256, 256, 0, stream>>>(ce, cc, vm, hcol, flag);

    dim3 gg(M_ / 128, H_ / 128);   // (128, 6)
    // h = gelu([hidden | hcol] @ [Wd | Wc]^T + bd + bc)
    gemm_bt<0, true, false><<<gg, 256, 0, stream>>>(hidden, hcol, Wd, Wc, bd, bc, nullptr, hbuf, 2 * H_, H_, flag);
    // q,k,v (head layout)
    gemm_bt<1, false, false><<<gg, 256, 0, stream>>>(hbuf, hbuf, Wq, Wq, bq, nullptr, nullptr, qb, H_, H_, flag);
    gemm_bt<1, false, false><<<gg, 256, 0, stream>>>(hbuf, hbuf, Wk, Wk, bk, nullptr, nullptr, kb, H_, H_, flag);
    gemm_bt<1, false, false><<<gg, 256, 0, stream>>>(hbuf, hbuf, Wv, Wv, bv, nullptr, nullptr, vb, H_, H_, flag);
    // attention (overwrites hcol as ctx)
    attn_kernel<<<dim3(S_ / 64, NH_, B_), 256, 0, stream>>>(qb, kb, vb, ctx);
    // y = ctx @ Wo^T + bo + h   (pre-layernorm, internal bf16; qb reused)
    gemm_bt<2, false, false><<<gg, 256, 0, stream>>>(ctx, ctx, Wo, Wo, bo, nullptr, hbuf, y, H_, H_, flag);
    // out = layernorm(y)*g + b  (output dtype per flag)
    ln_kernel<<<M_ / 4, 256, 0, stream>>>(y, lng, lnb, d_out, flag);
}

// Round 4
// 452.673 us; speedup vs baseline: 1.3945x; 1.3945x over previous
//
#include <hip/hip_runtime.h>
#include <hip/hip_bf16.h>
#include <math.h>
#include <stdint.h>

#define B_    32
#define S_    512
#define H_    768
#define NH_   12
#define HD_   64
#define NCOL_ 32
#define M_    (B_*S_)   // 16384

typedef __bf16 bf16;
typedef __bf16 bf16x8 __attribute__((ext_vector_type(8)));
typedef float  f32x4  __attribute__((ext_vector_type(4)));

// ---------------------------------------------------------------------------
// async global->LDS 16B copy (global_load_lds_dwordx4)
// ---------------------------------------------------------------------------
__device__ __forceinline__ void async_load16(const void* g, void* l) {
    __builtin_amdgcn_global_load_lds(
        (__attribute__((address_space(1))) unsigned int*)g,
        (__attribute__((address_space(3))) unsigned int*)l, 16, 0, 0);
}

// fp32 -> bf16x8 converting load (32B in)
__device__ __forceinline__ bf16x8 cvt8(const float* p) {
    const float4* fp = (const float4*)p;
    float4 x = fp[0], y = fp[1];
    bf16x8 r;
    r[0] = (bf16)x.x; r[1] = (bf16)x.y; r[2] = (bf16)x.z; r[3] = (bf16)x.w;
    r[4] = (bf16)y.x; r[5] = (bf16)y.y; r[6] = (bf16)y.z; r[7] = (bf16)y.w;
    return r;
}

// ---------------------------------------------------------------------------
// convert hidden -> hbf (bf16) and gathered column embeds -> hcol (bf16)
// id space: [0, 2*M_*96); first half hidden, second half gather
// ---------------------------------------------------------------------------
__global__ __launch_bounds__(256) void cvt_x_kernel(
    const float* __restrict__ hidden, const float* __restrict__ ce,
    const int* __restrict__ cc, const int* __restrict__ vm,
    bf16* __restrict__ hbf, bf16* __restrict__ hcol)
{
    int id = blockIdx.x * 256 + threadIdx.x;
    if (id < M_ * 96) {
        int row = id / 96, c = id - row * 96;
        *(bf16x8*)&hbf[(long)row * H_ + c * 8] = cvt8(hidden + (long)row * H_ + c * 8);
    } else {
        int cid = id - M_ * 96;
        int row = cid / 96, c = cid - row * 96;
        int b = row >> 9;
        int m = vm[row];
        bf16x8 val;
#pragma unroll
        for (int i = 0; i < 8; i++) val[i] = (bf16)0.0f;
        if (m > 0) {
            int col = m - 1;
            if (cc[b * NCOL_ + col] == 1)
                val = cvt8(ce + ((long)(b * NCOL_ + col)) * H_ + c * 8);
        }
        *(bf16x8*)&hcol[(long)row * H_ + c * 8] = val;
    }
}

// ---------------------------------------------------------------------------
// convert weights -> wpack (order: Wd,Wc,Wq,Wk,Wv,Wo) + packed qkv bias
// 6*73728 weight chunks of 8, then 288 bias chunks of 8
// ---------------------------------------------------------------------------
__global__ __launch_bounds__(256) void cvt_w_kernel(
    const float* __restrict__ Wd, const float* __restrict__ Wc,
    const float* __restrict__ Wq, const float* __restrict__ Wk,
    const float* __restrict__ Wv, const float* __restrict__ Wo,
    const float* __restrict__ bq, const float* __restrict__ bk,
    const float* __restrict__ bv, bf16* __restrict__ wpack,
    float* __restrict__ bqkv)
{
    int id = blockIdx.x * 256 + threadIdx.x;
    if (id < 442368) {
        const float* src;
        int r = id;
        if      (r < 73728)  { src = Wd; }
        else if (r < 147456) { src = Wc; r -= 73728; }
        else if (r < 221184) { src = Wq; r -= 147456; }
        else if (r < 294912) { src = Wk; r -= 221184; }
        else if (r < 368640) { src = Wv; r -= 294912; }
        else                 { src = Wo; r -= 368640; }
        *(bf16x8*)&wpack[(long)id * 8] = cvt8(src + (long)r * 8);
    } else if (id < 442656) {
        int j0 = (id - 442368) * 8;
#pragma unroll
        for (int i = 0; i < 8; i++) {
            int j = j0 + i;
            float v = (j < 768) ? bq[j] : (j < 1536) ? bk[j - 768] : bv[j - 1536];
            bqkv[j] = v;
        }
    }
}

// ---------------------------------------------------------------------------
// GEMM C[m,n] = sum_k A[m,k]*Bw[n,k]  (+ epilogue per MODE), all bf16, lda=ldb=768
// A/B split at KSPLIT (A0/A1, B0/B1). m97 structure: global_load_lds 16B staging.
// MODE 0: gelu(acc + bias1[n] + bias2[n]) -> out row-major [M,768] bf16
// MODE 1: acc + bias1[n] -> qkv triple buffer, [B,NH,S,HD] layout per section
// MODE 2: acc + bias1[n] + resid[m,n] -> out row-major [M,768] bf16 (in-place ok)
// ---------------------------------------------------------------------------
template<int MODE>
__global__ __launch_bounds__(256) void gemm_bt(
    const bf16* __restrict__ A0, const bf16* __restrict__ A1,
    const bf16* __restrict__ B0, const bf16* __restrict__ B1,
    const float* __restrict__ bias1, const float* __restrict__ bias2,
    const bf16* __restrict__ resid, bf16* __restrict__ out,
    int K, int KSPLIT)
{
    __shared__ __align__(16) bf16 As[128 * 32];
    __shared__ __align__(16) bf16 Bs[128 * 32];

    const int tid  = threadIdx.x;
    const int lane = tid & 63;
    const int wave = tid >> 6;
    const int wm   = wave & 1;
    const int wn   = wave >> 1;
    const int m0   = blockIdx.x * 128;
    const int n0   = blockIdx.y * 128;

    const int srow = tid >> 2;            // 0..63
    const int scol = (tid & 3) * 8;       // 0,8,16,24

    f32x4 acc[4][4];
    const f32x4 zero4 = {0.f, 0.f, 0.f, 0.f};
#pragma unroll
    for (int i = 0; i < 4; i++)
#pragma unroll
        for (int j = 0; j < 4; j++) acc[i][j] = zero4;

    const int a_off = (wm * 64 + (lane & 15)) * 32 + (lane >> 4) * 8;
    const int b_off = (wn * 64 + (lane & 15)) * 32 + (lane >> 4) * 8;

    for (int k0 = 0; k0 < K; k0 += 32) {
        const bf16* ag;
        const bf16* bg;
        if (k0 < KSPLIT) { ag = A0 + k0; bg = B0 + k0; }
        else             { ag = A1 + (k0 - KSPLIT); bg = B1 + (k0 - KSPLIT); }

        __syncthreads();   // prev iter's LDS reads done
        async_load16(ag + (long)(m0 + srow) * H_ + scol,       As + tid * 8);
        async_load16(ag + (long)(m0 + 64 + srow) * H_ + scol,  As + 2048 + tid * 8);
        async_load16(bg + (long)(n0 + srow) * H_ + scol,       Bs + tid * 8);
        async_load16(bg + (long)(n0 + 64 + srow) * H_ + scol,  Bs + 2048 + tid * 8);
        __syncthreads();   // async copies drained + visible

        bf16x8 af[4], bfr[4];
#pragma unroll
        for (int i = 0; i < 4; i++) af[i]  = *(const bf16x8*)(As + a_off + i * 512);
#pragma unroll
        for (int j = 0; j < 4; j++) bfr[j] = *(const bf16x8*)(Bs + b_off + j * 512);
#pragma unroll
        for (int i = 0; i < 4; i++)
#pragma unroll
            for (int j = 0; j < 4; j++)
                acc[i][j] = __builtin_amdgcn_mfma_f32_16x16x32_bf16(af[i], bfr[j], acc[i][j], 0, 0, 0);
    }

    const int c_r = (lane >> 4) * 4;
    const int c_c = lane & 15;

    // MODE 1 section select (n-block of 128 lies fully in one 768 section)
    int sec = 0;
    if (MODE == 1) sec = (n0 >= 1536) ? 2 : ((n0 >= 768) ? 1 : 0);
    bf16* dst = (MODE == 1) ? out + (long)sec * M_ * H_ : out;

#pragma unroll
    for (int j = 0; j < 4; j++) {
        const int col = n0 + wn * 64 + j * 16 + c_c;
        float bias = bias1[col];
        if (MODE == 0) bias += bias2[col];
#pragma unroll
        for (int i = 0; i < 4; i++) {
#pragma unroll
            for (int r = 0; r < 4; r++) {
                const int row = m0 + wm * 64 + i * 16 + c_r + r;
                float v = acc[i][j][r] + bias;
                if (MODE == 0) {
                    v = 0.5f * v * (1.0f + erff(v * 0.70710678118654752f));
                    dst[(long)row * H_ + col] = (bf16)v;
                } else if (MODE == 1) {
                    int b = row >> 9, s = row & 511;
                    int cs = col - sec * 768;
                    int head = cs >> 6, d = cs & 63;
                    dst[(((long)(b * NH_ + head)) * S_ + s) * HD_ + d] = (bf16)v;
                } else {
                    v += (float)resid[(long)row * H_ + col];
                    dst[(long)row * H_ + col] = (bf16)v;
                }
            }
        }
    }
}

// ---------------------------------------------------------------------------
// flash attention: one block per (qt, head, b); 64 q rows, k-chunks of 64.
// q,k,v internal [B,NH,S,HD] bf16. ctx out internal [B,S,H] bf16.
// ---------------------------------------------------------------------------
#define PS 88   // padded LDS row stride (elems): 176B, 16B-aligned

__global__ __launch_bounds__(256) void attn_kernel(
    const bf16* __restrict__ q, const bf16* __restrict__ k,
    const bf16* __restrict__ v, bf16* __restrict__ ctx)
{
    __shared__ __align__(16) bf16 Qs[64 * PS];
    __shared__ __align__(16) bf16 Ks[64 * PS];
    __shared__ __align__(16) bf16 Vt[64 * PS];      // transposed: Vt[d][s]
    __shared__ __align__(16) bf16 Ps[4][16 * PS];   // per-wave P tile

    const int tid  = threadIdx.x;
    const int lane = tid & 63;
    const int w    = tid >> 6;
    const int qt = blockIdx.x, h = blockIdx.y, b = blockIdx.z;
    const long base = ((long)(b * NH_ + h)) * S_ * HD_;

    {
        const bf16* qg = q + base + (long)qt * 64 * HD_;
        int c0 = tid * 2;
#pragma unroll
        for (int c = c0; c < c0 + 2; c++) {
            int row = c >> 3, cc = c & 7;
            *(uint4*)&Qs[row * PS + cc * 8] = *(const uint4*)&qg[row * HD_ + cc * 8];
        }
    }
    __syncthreads();

    const int fr = (lane >> 4) * 8;
    const bf16x8 aq0 = *(const bf16x8*)&Qs[(w * 16 + (lane & 15)) * PS + fr];
    const bf16x8 aq1 = *(const bf16x8*)&Qs[(w * 16 + (lane & 15)) * PS + 32 + fr];

    f32x4 O[4];
    const f32x4 zero4 = {0.f, 0.f, 0.f, 0.f};
#pragma unroll
    for (int t = 0; t < 4; t++) O[t] = zero4;
    float mo[4], l[4];
#pragma unroll
    for (int r = 0; r < 4; r++) { mo[r] = -1e30f; l[r] = 0.f; }

    const int vs = tid >> 2;          // s row for V transpose
    const int vd = (tid & 3) * 16;    // d base

    for (int kc = 0; kc < 8; kc++) {
        __syncthreads();
        const bf16* kg = k + base + (long)kc * 64 * HD_;
        const bf16* vg = v + base + (long)kc * 64 * HD_;
        {
            int c0 = tid * 2;
#pragma unroll
            for (int c = c0; c < c0 + 2; c++) {
                int row = c >> 3, cc = c & 7;
                *(uint4*)&Ks[row * PS + cc * 8] = *(const uint4*)&kg[row * HD_ + cc * 8];
            }
            uint4 p0 = *(const uint4*)&vg[vs * HD_ + vd];
            uint4 p1 = *(const uint4*)&vg[vs * HD_ + vd + 8];
            const bf16* e0 = (const bf16*)&p0;
            const bf16* e1 = (const bf16*)&p1;
#pragma unroll
            for (int i = 0; i < 8; i++) Vt[(vd + i) * PS + vs]     = e0[i];
#pragma unroll
            for (int i = 0; i < 8; i++) Vt[(vd + 8 + i) * PS + vs] = e1[i];
        }
        __syncthreads();

        f32x4 sc[4];
#pragma unroll
        for (int j = 0; j < 4; j++) {
            sc[j] = zero4;
            bf16x8 b0 = *(const bf16x8*)&Ks[(j * 16 + (lane & 15)) * PS + fr];
            bf16x8 b1 = *(const bf16x8*)&Ks[(j * 16 + (lane & 15)) * PS + 32 + fr];
            sc[j] = __builtin_amdgcn_mfma_f32_16x16x32_bf16(aq0, b0, sc[j], 0, 0, 0);
            sc[j] = __builtin_amdgcn_mfma_f32_16x16x32_bf16(aq1, b1, sc[j], 0, 0, 0);
        }

#pragma unroll
        for (int r = 0; r < 4; r++) {
            float s0 = sc[0][r] * 0.125f, s1 = sc[1][r] * 0.125f;
            float s2 = sc[2][r] * 0.125f, s3 = sc[3][r] * 0.125f;
            float rm = fmaxf(fmaxf(s0, s1), fmaxf(s2, s3));
            rm = fmaxf(rm, __shfl_xor(rm, 1));
            rm = fmaxf(rm, __shfl_xor(rm, 2));
            rm = fmaxf(rm, __shfl_xor(rm, 4));
            rm = fmaxf(rm, __shfl_xor(rm, 8));
            float mn = fmaxf(mo[r], rm);
            float alpha = __expf(mo[r] - mn);
            s0 = __expf(s0 - mn); s1 = __expf(s1 - mn);
            s2 = __expf(s2 - mn); s3 = __expf(s3 - mn);
            float rs = s0 + s1 + s2 + s3;
            rs += __shfl_xor(rs, 1);
            rs += __shfl_xor(rs, 2);
            rs += __shfl_xor(rs, 4);
            rs += __shfl_xor(rs, 8);
            l[r] = l[r] * alpha + rs;
            mo[r] = mn;
#pragma unroll
            for (int t = 0; t < 4; t++) O[t][r] *= alpha;
            int prow = (lane >> 4) * 4 + r;
            Ps[w][prow * PS +      (lane & 15)] = (bf16)s0;
            Ps[w][prow * PS + 16 + (lane & 15)] = (bf16)s1;
            Ps[w][prow * PS + 32 + (lane & 15)] = (bf16)s2;
            Ps[w][prow * PS + 48 + (lane & 15)] = (bf16)s3;
        }
        __syncthreads();

#pragma unroll
        for (int hh = 0; hh < 2; hh++) {
            bf16x8 ap = *(const bf16x8*)&Ps[w][(lane & 15) * PS + hh * 32 + fr];
#pragma unroll
            for (int t = 0; t < 4; t++) {
                bf16x8 bv = *(const bf16x8*)&Vt[(t * 16 + (lane & 15)) * PS + hh * 32 + fr];
                O[t] = __builtin_amdgcn_mfma_f32_16x16x32_bf16(ap, bv, O[t], 0, 0, 0);
            }
        }
    }

#pragma unroll
    for (int r = 0; r < 4; r++) {
        float inv = 1.0f / l[r];
        int s = qt * 64 + w * 16 + (lane >> 4) * 4 + r;
#pragma unroll
        for (int t = 0; t < 4; t++) {
            int d = t * 16 + (lane & 15);
            ctx[((long)(b * S_ + s)) * H_ + h * HD_ + d] = (bf16)(O[t][r] * inv);
        }
    }
}

// ---------------------------------------------------------------------------
// layernorm: one wave per row; bf16 in, fp32 out
// ---------------------------------------------------------------------------
__global__ __launch_bounds__(256) void ln_kernel(
    const bf16* __restrict__ y, const float* __restrict__ g,
    const float* __restrict__ be, float* __restrict__ out)
{
    const int lane = threadIdx.x & 63;
    const int w    = threadIdx.x >> 6;
    const long row = (long)blockIdx.x * 4 + w;
    const bf16* yr = y + row * H_;

    float x[12];
    float sum = 0.f, ss = 0.f;
#pragma unroll
    for (int j = 0; j < 12; j++) {
        x[j] = (float)yr[j * 64 + lane];
        sum += x[j];
        ss  += x[j] * x[j];
    }
#pragma unroll
    for (int m = 1; m < 64; m <<= 1) {
        sum += __shfl_xor(sum, m);
        ss  += __shfl_xor(ss, m);
    }
    const float mu  = sum * (1.0f / 768.0f);
    float var = ss * (1.0f / 768.0f) - mu * mu;
    const float rs = rsqrtf(fmaxf(var, 0.f) + 1e-12f);
#pragma unroll
    for (int j = 0; j < 12; j++) {
        int c = j * 64 + lane;
        out[row * H_ + c] = (x[j] - mu) * rs * g[c] + be[c];
    }
}

// ---------------------------------------------------------------------------
extern "C" void kernel_launch(void* const* d_in, const int* in_sizes, int n_in,
                              void* d_out, int out_size, void* d_ws, size_t ws_size,
                              hipStream_t stream)
{
    const float* hidden = (const float*)d_in[0];
    const float* ce     = (const float*)d_in[1];
    const int*   cc     = (const int*)d_in[2];
    const int*   vm     = (const int*)d_in[3];
    const float* Wd     = (const float*)d_in[4];
    const float* bd     = (const float*)d_in[5];
    const float* Wc     = (const float*)d_in[6];
    const float* bc     = (const float*)d_in[7];
    const float* Wq     = (const float*)d_in[8];
    const float* bq     = (const float*)d_in[9];
    const float* Wk     = (const float*)d_in[10];
    const float* bk     = (const float*)d_in[11];
    const float* Wv     = (const float*)d_in[12];
    const float* bv     = (const float*)d_in[13];
    const float* Wo     = (const float*)d_in[14];
    const float* bo     = (const float*)d_in[15];
    const float* lng    = (const float*)d_in[16];
    const float* lnb    = (const float*)d_in[17];

    // ---- workspace layout (bf16 elems; total ~102.8 MB) ----
    const long NE = (long)M_ * H_;            // 12,582,912 elems per buffer
    bf16* ws   = (bf16*)d_ws;
    bf16* hbuf = ws;                          // [0, NE)            gelu out / resid / y
    bf16* qkv  = ws + NE;                     // [NE, 4NE)          qb,kb,vb contiguous
    bf16* hbf  = qkv;                         //   hbf over qb   (dead before QKV GEMM writes)
    bf16* hcol = qkv + NE;                    //   hcol over kb  (same)
    bf16* qb   = qkv;
    bf16* kb   = qkv + NE;
    bf16* vb   = qkv + 2 * NE;
    bf16* wpack = ws + 4 * NE;                // 3,538,944 elems: Wd,Wc,Wq,Wk,Wv,Wo bf16
    const bf16* Wd_b  = wpack;
    const bf16* Wc_b  = wpack + 589824;
    const bf16* Wq_b  = wpack + 1179648;
    const bf16* Wk_b  = wpack + 1769472;
    const bf16* Wv_b  = wpack + 2359296;
    const bf16* Wo_b  = wpack + 2949120;
    float* bqkv = (float*)(wpack + 3538944);  // 2304 floats
    // ctx borrows d_out's first 25 MB (dead before LN overwrites all of d_out)
    bf16* ctx = (bf16*)d_out;

    // ---- pre-passes: fp32 -> bf16 conversion / gather / weight pack ----
    cvt_x_kernel<<<2 * M_ * 96 / 256, 256, 0, stream>>>(hidden, ce, cc, vm, hbf, hcol);
    cvt_w_kernel<<<1730, 256, 0, stream>>>(Wd, Wc, Wq, Wk, Wv, Wo, bq, bk, bv, wpack, bqkv);

    dim3 g6(M_ / 128, 6);     // 768 blocks
    dim3 g18(M_ / 128, 18);   // 2304 blocks
    // hbuf = gelu([hbf | hcol] @ [Wd | Wc]^T + bd + bc)
    gemm_bt<0><<<g6, 256, 0, stream>>>(hbf, hcol, Wd_b, Wc_b, bd, bc, nullptr, hbuf, 2 * H_, H_);
    // qkv = hbuf @ [Wq;Wk;Wv]^T + bqkv  (head layout, one fused GEMM)
    gemm_bt<1><<<g18, 256, 0, stream>>>(hbuf, hbuf, Wq_b, Wq_b, bqkv, nullptr, nullptr, qkv, H_, 3 * H_);
    // attention -> ctx (in d_out scratch)
    attn_kernel<<<dim3(S_ / 64, NH_, B_), 256, 0, stream>>>(qb, kb, vb, ctx);
    // hbuf = ctx @ Wo^T + bo + hbuf   (in-place residual)
    gemm_bt<2><<<g6, 256, 0, stream>>>(ctx, ctx, Wo_b, Wo_b, bo, nullptr, hbuf, hbuf, H_, H_);
    // d_out = layernorm(hbuf)*g + b   (fp32, overwrites ctx region)
    ln_kernel<<<M_ / 4, 256, 0, stream>>>(hbuf, lng, lnb, (float*)d_out);
}

// Round 5
// 430.942 us; speedup vs baseline: 1.4648x; 1.0504x over previous
//
#include <hip/hip_runtime.h>
#include <hip/hip_bf16.h>
#include <math.h>
#include <stdint.h>

#define B_    32
#define S_    512
#define H_    768
#define NH_   12
#define HD_   64
#define NCOL_ 32
#define M_    (B_*S_)   // 16384

typedef __bf16 bf16;
typedef __bf16 bf16x8 __attribute__((ext_vector_type(8)));
typedef __bf16 bf16x4 __attribute__((ext_vector_type(4)));
typedef float  f32x4  __attribute__((ext_vector_type(4)));

// ---------------------------------------------------------------------------
// async global->LDS 16B copy (global_load_lds_dwordx4)
// ---------------------------------------------------------------------------
__device__ __forceinline__ void async_load16(const void* g, void* l) {
    __builtin_amdgcn_global_load_lds(
        (__attribute__((address_space(1))) unsigned int*)g,
        (__attribute__((address_space(3))) unsigned int*)l, 16, 0, 0);
}

// fp32 -> bf16x8 converting load (32B in)
__device__ __forceinline__ bf16x8 cvt8(const float* p) {
    const float4* fp = (const float4*)p;
    float4 x = fp[0], y = fp[1];
    bf16x8 r;
    r[0] = (bf16)x.x; r[1] = (bf16)x.y; r[2] = (bf16)x.z; r[3] = (bf16)x.w;
    r[4] = (bf16)y.x; r[5] = (bf16)y.y; r[6] = (bf16)y.z; r[7] = (bf16)y.w;
    return r;
}

// ---------------------------------------------------------------------------
// convert hidden -> hbf (bf16) and gathered column embeds -> hcol (bf16)
// ---------------------------------------------------------------------------
__global__ __launch_bounds__(256) void cvt_x_kernel(
    const float* __restrict__ hidden, const float* __restrict__ ce,
    const int* __restrict__ cc, const int* __restrict__ vm,
    bf16* __restrict__ hbf, bf16* __restrict__ hcol)
{
    int id = blockIdx.x * 256 + threadIdx.x;
    if (id < M_ * 96) {
        int row = id / 96, c = id - row * 96;
        *(bf16x8*)&hbf[(long)row * H_ + c * 8] = cvt8(hidden + (long)row * H_ + c * 8);
    } else {
        int cid = id - M_ * 96;
        int row = cid / 96, c = cid - row * 96;
        int b = row >> 9;
        int m = vm[row];
        bf16x8 val;
#pragma unroll
        for (int i = 0; i < 8; i++) val[i] = (bf16)0.0f;
        if (m > 0) {
            int col = m - 1;
            if (cc[b * NCOL_ + col] == 1)
                val = cvt8(ce + ((long)(b * NCOL_ + col)) * H_ + c * 8);
        }
        *(bf16x8*)&hcol[(long)row * H_ + c * 8] = val;
    }
}

// ---------------------------------------------------------------------------
// convert weights -> wpack (order: Wd,Wc,Wq,Wk,Wv,Wo) + packed qkv bias
// ---------------------------------------------------------------------------
__global__ __launch_bounds__(256) void cvt_w_kernel(
    const float* __restrict__ Wd, const float* __restrict__ Wc,
    const float* __restrict__ Wq, const float* __restrict__ Wk,
    const float* __restrict__ Wv, const float* __restrict__ Wo,
    const float* __restrict__ bq, const float* __restrict__ bk,
    const float* __restrict__ bv, bf16* __restrict__ wpack,
    float* __restrict__ bqkv)
{
    int id = blockIdx.x * 256 + threadIdx.x;
    if (id < 442368) {
        const float* src;
        int r = id;
        if      (r < 73728)  { src = Wd; }
        else if (r < 147456) { src = Wc; r -= 73728; }
        else if (r < 221184) { src = Wq; r -= 147456; }
        else if (r < 294912) { src = Wk; r -= 221184; }
        else if (r < 368640) { src = Wv; r -= 294912; }
        else                 { src = Wo; r -= 368640; }
        *(bf16x8*)&wpack[(long)id * 8] = cvt8(src + (long)r * 8);
    } else if (id < 442656) {
        int j0 = (id - 442368) * 8;
#pragma unroll
        for (int i = 0; i < 8; i++) {
            int j = j0 + i;
            float v = (j < 768) ? bq[j] : (j < 1536) ? bk[j - 768] : bv[j - 1536];
            bqkv[j] = v;
        }
    }
}

// ---------------------------------------------------------------------------
// GEMM C[m,n] = sum_k A[m,k]*Bw[n,k]  (+ epilogue per MODE), all bf16, lda=ldb=768
// MODE 0: gelu(acc + bias1[n] + bias2[n]) -> [M,768] bf16
// MODE 1: acc + bias1[n] -> qkv: Q,K sections [B,NH,S,HD]; V section [B,NH,HD,S]
// MODE 2: acc + bias1[n] + resid[m,n] -> [M,768] bf16 (in-place ok)
// ---------------------------------------------------------------------------
template<int MODE>
__global__ __launch_bounds__(256) void gemm_bt(
    const bf16* __restrict__ A0, const bf16* __restrict__ A1,
    const bf16* __restrict__ B0, const bf16* __restrict__ B1,
    const float* __restrict__ bias1, const float* __restrict__ bias2,
    const bf16* __restrict__ resid, bf16* __restrict__ out,
    int K, int KSPLIT)
{
    __shared__ __align__(16) bf16 As[128 * 32];
    __shared__ __align__(16) bf16 Bs[128 * 32];

    const int tid  = threadIdx.x;
    const int lane = tid & 63;
    const int wave = tid >> 6;
    const int wm   = wave & 1;
    const int wn   = wave >> 1;
    const int m0   = blockIdx.x * 128;
    const int n0   = blockIdx.y * 128;

    const int srow = tid >> 2;            // 0..63
    const int scol = (tid & 3) * 8;       // 0,8,16,24

    f32x4 acc[4][4];
    const f32x4 zero4 = {0.f, 0.f, 0.f, 0.f};
#pragma unroll
    for (int i = 0; i < 4; i++)
#pragma unroll
        for (int j = 0; j < 4; j++) acc[i][j] = zero4;

    const int a_off = (wm * 64 + (lane & 15)) * 32 + (lane >> 4) * 8;
    const int b_off = (wn * 64 + (lane & 15)) * 32 + (lane >> 4) * 8;

    for (int k0 = 0; k0 < K; k0 += 32) {
        const bf16* ag;
        const bf16* bg;
        if (k0 < KSPLIT) { ag = A0 + k0; bg = B0 + k0; }
        else             { ag = A1 + (k0 - KSPLIT); bg = B1 + (k0 - KSPLIT); }

        __syncthreads();   // prev iter's LDS reads done
        async_load16(ag + (long)(m0 + srow) * H_ + scol,       As + tid * 8);
        async_load16(ag + (long)(m0 + 64 + srow) * H_ + scol,  As + 2048 + tid * 8);
        async_load16(bg + (long)(n0 + srow) * H_ + scol,       Bs + tid * 8);
        async_load16(bg + (long)(n0 + 64 + srow) * H_ + scol,  Bs + 2048 + tid * 8);
        __syncthreads();   // async copies drained + visible

        bf16x8 af[4], bfr[4];
#pragma unroll
        for (int i = 0; i < 4; i++) af[i]  = *(const bf16x8*)(As + a_off + i * 512);
#pragma unroll
        for (int j = 0; j < 4; j++) bfr[j] = *(const bf16x8*)(Bs + b_off + j * 512);
#pragma unroll
        for (int i = 0; i < 4; i++)
#pragma unroll
            for (int j = 0; j < 4; j++)
                acc[i][j] = __builtin_amdgcn_mfma_f32_16x16x32_bf16(af[i], bfr[j], acc[i][j], 0, 0, 0);
    }

    const int c_r = (lane >> 4) * 4;
    const int c_c = lane & 15;

    int sec = 0;
    if (MODE == 1) sec = (n0 >= 1536) ? 2 : ((n0 >= 768) ? 1 : 0);
    bf16* dst = (MODE == 1) ? out + (long)sec * M_ * H_ : out;

#pragma unroll
    for (int j = 0; j < 4; j++) {
        const int col = n0 + wn * 64 + j * 16 + c_c;
        float bias = bias1[col];
        if (MODE == 0) bias += bias2[col];
#pragma unroll
        for (int i = 0; i < 4; i++) {
#pragma unroll
            for (int r = 0; r < 4; r++) {
                const int row = m0 + wm * 64 + i * 16 + c_r + r;
                float v = acc[i][j][r] + bias;
                if (MODE == 0) {
                    v = 0.5f * v * (1.0f + erff(v * 0.70710678118654752f));
                    dst[(long)row * H_ + col] = (bf16)v;
                } else if (MODE == 1) {
                    int b = row >> 9, s = row & 511;
                    int cs = col - sec * 768;
                    int head = cs >> 6, d = cs & 63;
                    if (sec == 2)   // V stored transposed: [B,NH,HD,S]
                        dst[(((long)(b * NH_ + head)) * HD_ + d) * S_ + s] = (bf16)v;
                    else
                        dst[(((long)(b * NH_ + head)) * S_ + s) * HD_ + d] = (bf16)v;
                } else {
                    v += (float)resid[(long)row * H_ + col];
                    dst[(long)row * H_ + col] = (bf16)v;
                }
            }
        }
    }
}

// ---------------------------------------------------------------------------
// flash attention, transposed-score form.
// grid: 3072 1-D blocks, qt-major so all 8 qt of a (b,h) share an XCD L2.
// q,k in [B,NH,S,HD]; v PRE-TRANSPOSED [B,NH,HD,S]; ctx out [B,S,H] bf16.
// Per wave: 16 q rows. S^T = K @ Q^T (col = q = lane&15, row = t).
// Softmax in-lane over 16 t + 2 shuffles. PV: O^T = V^T @ P^T.
// Register double-buffer of next K/V chunk.
// ---------------------------------------------------------------------------
#define QP 72   // LDS row stride (elems) for Qs/Ks/Vt/Ps: 144 B, 16B-aligned

__global__ __launch_bounds__(256) void attn_kernel(
    const bf16* __restrict__ q, const bf16* __restrict__ k,
    const bf16* __restrict__ vt, bf16* __restrict__ ctx)
{
    __shared__ __align__(16) bf16 Qs[64 * QP];
    __shared__ __align__(16) bf16 Ks[64 * QP];
    __shared__ __align__(16) bf16 Vt[64 * QP];      // V^T chunk: [d][t]
    __shared__ __align__(16) bf16 Ps[4][16 * QP];   // per-wave P: [q][t]

    const int tid  = threadIdx.x;
    const int lane = tid & 63;
    const int w    = tid >> 6;
    const int quad = lane >> 4;
    const int ln16 = lane & 15;

    const int bid = blockIdx.x;
    const int qt  = bid / 384;          // qt-major: same g -> same XCD (384%8==0)
    const int g   = bid - qt * 384;
    const int b   = g / 12;
    const int h   = g - b * 12;
    const long base = ((long)(b * NH_ + h)) * S_ * HD_;

    // staging map: 2 uint4/thread covering a 64x64 bf16 tile
    const int r0 = tid >> 2;            // row 0..63
    const int e0 = (tid & 3) * 16;      // col elems 0,16,32,48

    // ---- load Q tile [64 q][64 d]
    {
        const bf16* qg = q + base + (long)qt * 64 * HD_;
        *(uint4*)&Qs[r0 * QP + e0]     = *(const uint4*)&qg[r0 * HD_ + e0];
        *(uint4*)&Qs[r0 * QP + e0 + 8] = *(const uint4*)&qg[r0 * HD_ + e0 + 8];
    }
    // ---- preload chunk 0 of K and V^T into regs
    const bf16* kg = k  + base;
    const bf16* vg = vt + base;
    uint4 kr0 = *(const uint4*)&kg[r0 * HD_ + e0];
    uint4 kr1 = *(const uint4*)&kg[r0 * HD_ + e0 + 8];
    uint4 vr0 = *(const uint4*)&vg[(long)r0 * S_ + e0];
    uint4 vr1 = *(const uint4*)&vg[(long)r0 * S_ + e0 + 8];
    __syncthreads();

    // Q as B-operand: B[k=d][n=q], n = lane&15
    const bf16x8 bq0 = *(const bf16x8*)&Qs[(w * 16 + ln16) * QP + quad * 8];
    const bf16x8 bq1 = *(const bf16x8*)&Qs[(w * 16 + ln16) * QP + 32 + quad * 8];

    f32x4 O[4];   // O^T: O[dt][r] = O^T[d = dt*16+quad*4+r][q = ln16]
    const f32x4 zero4 = {0.f, 0.f, 0.f, 0.f};
#pragma unroll
    for (int t = 0; t < 4; t++) O[t] = zero4;
    float mo = -1e30f, l = 0.f;   // per-lane (per-q, replicated across quads)

    for (int kc = 0; kc < 8; kc++) {
        __syncthreads();   // prev iter LDS reads complete
        *(uint4*)&Ks[r0 * QP + e0]     = kr0;
        *(uint4*)&Ks[r0 * QP + e0 + 8] = kr1;
        *(uint4*)&Vt[r0 * QP + e0]     = vr0;
        *(uint4*)&Vt[r0 * QP + e0 + 8] = vr1;
        // prefetch next chunk (regs); latency hides behind this iter's compute
        {
            int kcn = (kc < 7) ? kc + 1 : 7;
            kr0 = *(const uint4*)&kg[(long)kcn * 64 * HD_ + r0 * HD_ + e0];
            kr1 = *(const uint4*)&kg[(long)kcn * 64 * HD_ + r0 * HD_ + e0 + 8];
            vr0 = *(const uint4*)&vg[(long)r0 * S_ + kcn * 64 + e0];
            vr1 = *(const uint4*)&vg[(long)r0 * S_ + kcn * 64 + e0 + 8];
        }
        __syncthreads();   // staging visible

        // ---- S^T = K @ Q^T : sc[i] = tile [t = i*16..][q16]
        f32x4 sc[4];
#pragma unroll
        for (int i = 0; i < 4; i++) {
            bf16x8 a0 = *(const bf16x8*)&Ks[(i * 16 + ln16) * QP + quad * 8];
            bf16x8 a1 = *(const bf16x8*)&Ks[(i * 16 + ln16) * QP + 32 + quad * 8];
            sc[i] = zero4;
            sc[i] = __builtin_amdgcn_mfma_f32_16x16x32_bf16(a0, bq0, sc[i], 0, 0, 0);
            sc[i] = __builtin_amdgcn_mfma_f32_16x16x32_bf16(a1, bq1, sc[i], 0, 0, 0);
        }

        // ---- online softmax: 16 t-values per lane for q = ln16
        float cm = -1e30f;
#pragma unroll
        for (int i = 0; i < 4; i++)
#pragma unroll
            for (int r = 0; r < 4; r++) {
                float s = sc[i][r] * 0.125f;
                sc[i][r] = s;
                cm = fmaxf(cm, s);
            }
        cm = fmaxf(cm, __shfl_xor(cm, 16));
        cm = fmaxf(cm, __shfl_xor(cm, 32));
        float mn = fmaxf(mo, cm);
        float alpha = __expf(mo - mn);
        float rs = 0.f;
#pragma unroll
        for (int i = 0; i < 4; i++) {
            bf16x4 pk;
#pragma unroll
            for (int r = 0; r < 4; r++) {
                float p = __expf(sc[i][r] - mn);
                rs += p;
                pk[r] = (bf16)p;
            }
            *(bf16x4*)&Ps[w][ln16 * QP + i * 16 + quad * 4] = pk;
        }
        rs += __shfl_xor(rs, 16);
        rs += __shfl_xor(rs, 32);
        l  = l * alpha + rs;
        mo = mn;
#pragma unroll
        for (int t = 0; t < 4; t++)
#pragma unroll
            for (int r = 0; r < 4; r++) O[t][r] *= alpha;

        // ---- PV: O^T += V^T @ P^T  (wave-private Ps; waitcnt only, no barrier)
        bf16x8 bp0 = *(const bf16x8*)&Ps[w][ln16 * QP + quad * 8];
        bf16x8 bp1 = *(const bf16x8*)&Ps[w][ln16 * QP + 32 + quad * 8];
#pragma unroll
        for (int dt = 0; dt < 4; dt++) {
            bf16x8 a0 = *(const bf16x8*)&Vt[(dt * 16 + ln16) * QP + quad * 8];
            bf16x8 a1 = *(const bf16x8*)&Vt[(dt * 16 + ln16) * QP + 32 + quad * 8];
            O[dt] = __builtin_amdgcn_mfma_f32_16x16x32_bf16(a0, bp0, O[dt], 0, 0, 0);
            O[dt] = __builtin_amdgcn_mfma_f32_16x16x32_bf16(a1, bp1, O[dt], 0, 0, 0);
        }
    }

    // ---- epilogue: O^T -> LDS (reuse Qs) -> coalesced ctx write
    {
        float inv = 1.0f / l;
#pragma unroll
        for (int dt = 0; dt < 4; dt++) {
            bf16x4 ov;
#pragma unroll
            for (int r = 0; r < 4; r++) ov[r] = (bf16)(O[dt][r] * inv);
            *(bf16x4*)&Qs[(w * 16 + ln16) * QP + dt * 16 + quad * 4] = ov;
        }
    }
    __syncthreads();
    {
        uint4 o0 = *(const uint4*)&Qs[r0 * QP + e0];
        uint4 o1 = *(const uint4*)&Qs[r0 * QP + e0 + 8];
        bf16* cg = ctx + ((long)(b * S_ + qt * 64 + r0)) * H_ + h * HD_;
        *(uint4*)&cg[e0]     = o0;
        *(uint4*)&cg[e0 + 8] = o1;
    }
}

// ---------------------------------------------------------------------------
// layernorm: one wave per row; bf16 in, fp32 out
// ---------------------------------------------------------------------------
__global__ __launch_bounds__(256) void ln_kernel(
    const bf16* __restrict__ y, const float* __restrict__ g,
    const float* __restrict__ be, float* __restrict__ out)
{
    const int lane = threadIdx.x & 63;
    const int w    = threadIdx.x >> 6;
    const long row = (long)blockIdx.x * 4 + w;
    const bf16* yr = y + row * H_;

    float x[12];
    float sum = 0.f, ss = 0.f;
#pragma unroll
    for (int j = 0; j < 12; j++) {
        x[j] = (float)yr[j * 64 + lane];
        sum += x[j];
        ss  += x[j] * x[j];
    }
#pragma unroll
    for (int m = 1; m < 64; m <<= 1) {
        sum += __shfl_xor(sum, m);
        ss  += __shfl_xor(ss, m);
    }
    const float mu  = sum * (1.0f / 768.0f);
    float var = ss * (1.0f / 768.0f) - mu * mu;
    const float rs = rsqrtf(fmaxf(var, 0.f) + 1e-12f);
#pragma unroll
    for (int j = 0; j < 12; j++) {
        int c = j * 64 + lane;
        out[row * H_ + c] = (x[j] - mu) * rs * g[c] + be[c];
    }
}

// ---------------------------------------------------------------------------
extern "C" void kernel_launch(void* const* d_in, const int* in_sizes, int n_in,
                              void* d_out, int out_size, void* d_ws, size_t ws_size,
                              hipStream_t stream)
{
    const float* hidden = (const float*)d_in[0];
    const float* ce     = (const float*)d_in[1];
    const int*   cc     = (const int*)d_in[2];
    const int*   vm     = (const int*)d_in[3];
    const float* Wd     = (const float*)d_in[4];
    const float* bd     = (const float*)d_in[5];
    const float* Wc     = (const float*)d_in[6];
    const float* bc     = (const float*)d_in[7];
    const float* Wq     = (const float*)d_in[8];
    const float* bq     = (const float*)d_in[9];
    const float* Wk     = (const float*)d_in[10];
    const float* bk     = (const float*)d_in[11];
    const float* Wv     = (const float*)d_in[12];
    const float* bv     = (const float*)d_in[13];
    const float* Wo     = (const float*)d_in[14];
    const float* bo     = (const float*)d_in[15];
    const float* lng    = (const float*)d_in[16];
    const float* lnb    = (const float*)d_in[17];

    // ---- workspace layout (bf16 elems; total ~102.8 MB) ----
    const long NE = (long)M_ * H_;
    bf16* ws   = (bf16*)d_ws;
    bf16* hbuf = ws;                          // gelu out / resid / y
    bf16* qkv  = ws + NE;                     // qb,kb,vb contiguous
    bf16* hbf  = qkv;                         // hbf over qb (dead before QKV writes)
    bf16* hcol = qkv + NE;                    // hcol over kb
    bf16* qb   = qkv;
    bf16* kb   = qkv + NE;
    bf16* vb   = qkv + 2 * NE;                // V^T layout [B,NH,HD,S]
    bf16* wpack = ws + 4 * NE;
    const bf16* Wd_b  = wpack;
    const bf16* Wc_b  = wpack + 589824;
    const bf16* Wq_b  = wpack + 1179648;
    const bf16* Wk_b  = wpack + 1769472;
    const bf16* Wv_b  = wpack + 2359296;
    const bf16* Wo_b  = wpack + 2949120;
    float* bqkv = (float*)(wpack + 3538944);
    bf16* ctx = (bf16*)d_out;                 // borrow d_out (dead before LN)

    cvt_x_kernel<<<2 * M_ * 96 / 256, 256, 0, stream>>>(hidden, ce, cc, vm, hbf, hcol);
    cvt_w_kernel<<<1730, 256, 0, stream>>>(Wd, Wc, Wq, Wk, Wv, Wo, bq, bk, bv, wpack, bqkv);

    dim3 g6(M_ / 128, 6);
    dim3 g18(M_ / 128, 18);
    gemm_bt<0><<<g6, 256, 0, stream>>>(hbf, hcol, Wd_b, Wc_b, bd, bc, nullptr, hbuf, 2 * H_, H_);
    gemm_bt<1><<<g18, 256, 0, stream>>>(hbuf, hbuf, Wq_b, Wq_b, bqkv, nullptr, nullptr, qkv, H_, 3 * H_);
    attn_kernel<<<3072, 256, 0, stream>>>(qb, kb, vb, ctx);
    gemm_bt<2><<<g6, 256, 0, stream>>>(ctx, ctx, Wo_b, Wo_b, bo, nullptr, hbuf, hbuf, H_, H_);
    ln_kernel<<<M_ / 4, 256, 0, stream>>>(hbuf, lng, lnb, (float*)d_out);
}